// Round 6
// baseline (510.910 us; speedup 1.0000x reference)
//
#include <hip/hip_runtime.h>

#define NG 72

// ---------------- conv1: (64,216,46,46) -> k5 g72 (3->8) -> relu -> pool2 -> (64,576,21,21)
// Thread = (pooled-y, pooled-x pair): 2 pooled outputs, 8 pre-pool points, all 8 oc
// in two 4-oc halves. Rolling 2-row register window; weights padded to 8/ky-row.
#define C1_PITCH 50
__global__ __launch_bounds__(256) void conv1_k(const float* __restrict__ x,
                                               const float* __restrict__ w,
                                               const float* __restrict__ bias,
                                               float* __restrict__ out) {
  const int b = blockIdx.x / NG, g = blockIdx.x % NG;
  __shared__ float sx[3 * 46 * C1_PITCH + 16];  // pitch 50: spreads banks, 8B-aligned rows
  __shared__ float sw[8 * 3 * 5 * 8];           // [oc][ic][ky][8] (5 used): 16B-aligned rows
  __shared__ float sb[8];
  const float* xp = x + (size_t)(b * 216 + g * 3) * 2116;
  const float4* xp4 = (const float4*)xp;   // 3*2116 = 6348 = 1587 float4
  for (int i = threadIdx.x; i < 1587; i += 256) {
    const float4 v = xp4[i];
#pragma unroll
    for (int j = 0; j < 4; j++) {
      const int k = 4 * i + j;
      const int ic = k / 2116, rem = k % 2116, r = rem / 46, c = rem % 46;
      sx[(ic * 46 + r) * C1_PITCH + c] = (&v.x)[j];
    }
  }
  const float* wp = w + (size_t)(g * 8) * 75;
  for (int i = threadIdx.x; i < 600; i += 256) {
    const int oc = i / 75, rem = i % 75, ic = rem / 25, k = rem % 25;
    sw[((oc * 3 + ic) * 5 + k / 5) * 8 + k % 5] = wp[i];
  }
  if (threadIdx.x < 8) sb[threadIdx.x] = bias[g * 8 + threadIdx.x];
  __syncthreads();
  const int tid = threadIdx.x;
  if (tid < 231) {                       // 21 y * 11 x-pairs
    const int y = tid / 11, t = tid % 11;
    const int iy = 2 * y, ix0 = 4 * t;   // pre-pool col base (pair covers pooled 2t,2t+1)
#pragma unroll 1   // sequential halves: do NOT merge live ranges
    for (int half = 0; half < 2; half++) {
      float acc[4][8];                   // [oc][row*4+col], pre-pool points
#pragma unroll
      for (int o = 0; o < 4; o++)
#pragma unroll
        for (int q = 0; q < 8; q++) acc[o][q] = 0.f;
#pragma unroll
      for (int ic = 0; ic < 3; ic++) {
        const float* rb = &sx[(ic * 46) * C1_PITCH + ix0];
        float R0[8], R1[8];
#pragma unroll
        for (int j2 = 0; j2 < 4; j2++) {
          const float2 v = *(const float2*)&rb[iy * C1_PITCH + 2 * j2];
          R0[2 * j2] = v.x; R0[2 * j2 + 1] = v.y;
        }
#pragma unroll
        for (int ky = 0; ky < 5; ky++) {
#pragma unroll
          for (int j2 = 0; j2 < 4; j2++) {
            const float2 v = *(const float2*)&rb[(iy + ky + 1) * C1_PITCH + 2 * j2];
            R1[2 * j2] = v.x; R1[2 * j2 + 1] = v.y;
          }
#pragma unroll
          for (int o4 = 0; o4 < 4; o4++) {
            const int oc = half * 4 + o4;
            const float4 wA = *(const float4*)&sw[((oc * 3 + ic) * 5 + ky) * 8];
            const float  wB = sw[((oc * 3 + ic) * 5 + ky) * 8 + 4];
            const float wv[5] = {wA.x, wA.y, wA.z, wA.w, wB};
#pragma unroll
            for (int kx = 0; kx < 5; kx++) {
#pragma unroll
              for (int j = 0; j < 4; j++) {
                acc[o4][j]     = fmaf(R0[j + kx], wv[kx], acc[o4][j]);
                acc[o4][4 + j] = fmaf(R1[j + kx], wv[kx], acc[o4][4 + j]);
              }
            }
          }
#pragma unroll
          for (int j = 0; j < 8; j++) R0[j] = R1[j];   // roll (renamed away when unrolled)
        }
      }
#pragma unroll
      for (int o4 = 0; o4 < 4; o4++) {
        const int oc = half * 4 + o4;
        const float v0 = fmaxf(fmaxf(acc[o4][0], acc[o4][1]), fmaxf(acc[o4][4], acc[o4][5])) + sb[oc];
        const float v1 = fmaxf(fmaxf(acc[o4][2], acc[o4][3]), fmaxf(acc[o4][6], acc[o4][7])) + sb[oc];
        float* op = &out[(size_t)(b * 576 + g * 8 + oc) * 441 + y * 21 + 2 * t];
        op[0] = fmaxf(v0, 0.f);
        if (2 * t + 1 < 21) op[1] = fmaxf(v1, 0.f);
      }
    }
  }
}

// ---------------- conv2: (64,576,21,21) -> k3 (8->16) -> relu -> pool2 -> (64,1152,9,9)
#define C2_NBB 3
__global__ __launch_bounds__(256) void conv2_k(const float* __restrict__ x,
                                               const float* __restrict__ w,
                                               const float* __restrict__ bias,
                                               float* __restrict__ out) {
  const int g = blockIdx.x % NG, b0 = (blockIdx.x / NG) * C2_NBB;
  const int nbb = min(C2_NBB, 64 - b0);
  __shared__ float sx[C2_NBB][8][21][22];
  __shared__ float sw[16 * 8 * 12];     // [oc][ic][12] (9 used), float4-aligned
  __shared__ float sb[16];
  for (int bb = 0; bb < nbb; bb++) {
    const float* xp = x + (size_t)((b0 + bb) * 576 + g * 8) * 441;
    for (int i = threadIdx.x; i < 8 * 441; i += 256) {
      const int ic = i / 441, rem = i % 441, r = rem / 21, c = rem % 21;
      sx[bb][ic][r][c] = xp[i];
    }
  }
  const float* wp = w + (size_t)(g * 16) * 72;
  for (int i = threadIdx.x; i < 16 * 72; i += 256) {
    const int oc = i / 72, rem = i % 72, ic = rem / 9, k = rem % 9;
    sw[(oc * 8 + ic) * 12 + k] = wp[i];
  }
  if (threadIdx.x < 16) sb[threadIdx.x] = bias[g * 16 + threadIdx.x];
  __syncthreads();
  for (int u = threadIdx.x; u < nbb * 81; u += 256) {
    const int bb = u / 81, p = u % 81, py = p / 9, px = p % 9;
    const int iy = 2 * py, ix = 2 * px;
#pragma unroll 1   // sequential halves
    for (int half = 0; half < 2; half++) {
      float acc[8][4];
#pragma unroll
      for (int o = 0; o < 8; o++)
#pragma unroll
        for (int q = 0; q < 4; q++) acc[o][q] = 0.f;
#pragma unroll
      for (int ic = 0; ic < 8; ic++) {
        float win[4][4];
#pragma unroll
        for (int r = 0; r < 4; r++) {
          const float2 a = *(const float2*)&sx[bb][ic][iy + r][ix];
          const float2 c2 = *(const float2*)&sx[bb][ic][iy + r][ix + 2];
          win[r][0] = a.x; win[r][1] = a.y; win[r][2] = c2.x; win[r][3] = c2.y;
        }
#pragma unroll
        for (int o8 = 0; o8 < 8; o8++) {
          const int oc = half * 8 + o8;
          const float4 wA = *(const float4*)&sw[(oc * 8 + ic) * 12];
          const float4 wB = *(const float4*)&sw[(oc * 8 + ic) * 12 + 4];
          const float  w8 = sw[(oc * 8 + ic) * 12 + 8];
          const float wv[9] = {wA.x, wA.y, wA.z, wA.w, wB.x, wB.y, wB.z, wB.w, w8};
#pragma unroll
          for (int ky = 0; ky < 3; ky++)
#pragma unroll
            for (int kx = 0; kx < 3; kx++) {
              const float wv_ = wv[ky * 3 + kx];
              acc[o8][0] = fmaf(win[ky][kx],         wv_, acc[o8][0]);
              acc[o8][1] = fmaf(win[ky][kx + 1],     wv_, acc[o8][1]);
              acc[o8][2] = fmaf(win[ky + 1][kx],     wv_, acc[o8][2]);
              acc[o8][3] = fmaf(win[ky + 1][kx + 1], wv_, acc[o8][3]);
            }
        }
      }
#pragma unroll
      for (int o8 = 0; o8 < 8; o8++) {
        const int oc = half * 8 + o8;
        const float v = fmaxf(fmaxf(acc[o8][0], acc[o8][1]), fmaxf(acc[o8][2], acc[o8][3])) + sb[oc];
        out[(size_t)((b0 + bb) * 1152 + g * 16 + oc) * 81 + p] = fmaxf(v, 0.f);
      }
    }
  }
}

// ---------------- conv3: (64,1152,9,9) -> k3 (16->32) -> relu -> pool2 -> (64,2304,3,3)
// ocg = wave id -> weight reads are wave-uniform broadcasts (conflict-free).
#define C3_NBB 7
__global__ __launch_bounds__(256) void conv3_k(const float* __restrict__ x,
                                               const float* __restrict__ w,
                                               const float* __restrict__ bias,
                                               float* __restrict__ out) {
  const int g = blockIdx.x % NG, b0 = (blockIdx.x / NG) * C3_NBB;
  const int nbb = min(C3_NBB, 64 - b0);
  __shared__ float sx[C3_NBB][16 * 90 + 2];  // per-ic [9][10] pitch-10; +2 spreads bb banks
  __shared__ float sw[32 * 16 * 12];         // [oc][ic][12] (9 used)
  __shared__ float sb[32];
  for (int bb = 0; bb < nbb; bb++) {
    const float* xp = x + (size_t)((b0 + bb) * 1152 + g * 16) * 81;
    for (int i = threadIdx.x; i < 16 * 81; i += 256) {
      const int ic = i / 81, rem = i % 81, r = rem / 9, c = rem % 9;
      sx[bb][ic * 90 + r * 10 + c] = xp[i];
    }
  }
  const float* wp = w + (size_t)(g * 32) * 144;
  for (int i = threadIdx.x; i < 32 * 144; i += 256) {
    const int oc = i / 144, rem = i % 144, ic = rem / 9, k = rem % 9;
    sw[(oc * 16 + ic) * 12 + k] = wp[i];
  }
  if (threadIdx.x < 32) sb[threadIdx.x] = bias[g * 32 + threadIdx.x];
  __syncthreads();
  const int ocg = threadIdx.x >> 6;          // wave-uniform oc group (4 waves x 8 oc)
  const int lane = threadIdx.x & 63;
  const int bb = lane / 9, p = lane % 9;     // 7 bb x 9 points (lane 63 idle)
  if (bb < nbb) {
    const int py = p / 3, px = p % 3, iy = 2 * py, ix = 2 * px;
    const float* sxb = &sx[bb][0];
    float acc[8][4];
#pragma unroll
    for (int o = 0; o < 8; o++)
#pragma unroll
      for (int q = 0; q < 4; q++) acc[o][q] = 0.f;
#pragma unroll
    for (int ic = 0; ic < 16; ic++) {
      float win[4][4];
#pragma unroll
      for (int r = 0; r < 4; r++) {
        const float2 a = *(const float2*)&sxb[ic * 90 + (iy + r) * 10 + ix];
        const float2 c2 = *(const float2*)&sxb[ic * 90 + (iy + r) * 10 + ix + 2];
        win[r][0] = a.x; win[r][1] = a.y; win[r][2] = c2.x; win[r][3] = c2.y;
      }
#pragma unroll
      for (int o8 = 0; o8 < 8; o8++) {
        const int oc = ocg * 8 + o8;         // wave-uniform -> broadcast reads
        const float4 wA = *(const float4*)&sw[(oc * 16 + ic) * 12];
        const float4 wB = *(const float4*)&sw[(oc * 16 + ic) * 12 + 4];
        const float  w8 = sw[(oc * 16 + ic) * 12 + 8];
        const float wv[9] = {wA.x, wA.y, wA.z, wA.w, wB.x, wB.y, wB.z, wB.w, w8};
#pragma unroll
        for (int ky = 0; ky < 3; ky++)
#pragma unroll
          for (int kx = 0; kx < 3; kx++) {
            const float wv_ = wv[ky * 3 + kx];
            acc[o8][0] = fmaf(win[ky][kx],         wv_, acc[o8][0]);
            acc[o8][1] = fmaf(win[ky][kx + 1],     wv_, acc[o8][1]);
            acc[o8][2] = fmaf(win[ky + 1][kx],     wv_, acc[o8][2]);
            acc[o8][3] = fmaf(win[ky + 1][kx + 1], wv_, acc[o8][3]);
          }
      }
    }
#pragma unroll
    for (int o8 = 0; o8 < 8; o8++) {
      const int oc = ocg * 8 + o8;
      const float v = fmaxf(fmaxf(acc[o8][0], acc[o8][1]), fmaxf(acc[o8][2], acc[o8][3])) + sb[oc];
      out[(size_t)((b0 + bb) * 2304 + g * 32 + oc) * 9 + p] = fmaxf(v, 0.f);
    }
  }
}

// ---------------- fused block-diagonal linear1 (288->64) + linear2 (64->2) + bias
__global__ __launch_bounds__(256) void lin_k(const float* __restrict__ h,
                                             const float* __restrict__ w1,
                                             const float* __restrict__ w2,
                                             const float* __restrict__ b2,
                                             float* __restrict__ out) {
  const int g = blockIdx.x % NG, b0 = (blockIdx.x / NG) * 32;
  __shared__ float sw1[64 * 292];
  __shared__ float sf[32 * 300];
  __shared__ float so[32 * 65];
  __shared__ float sw2[2 * 64];
  __shared__ float sb2[2];
  for (int i = threadIdx.x; i < 64 * 288; i += 256) {
    const int o = i / 288, k = i % 288;
    sw1[o * 292 + k] = w1[(size_t)(g * 64 + o) * 20736 + g * 288 + k];
  }
  for (int i = threadIdx.x; i < 32 * 288; i += 256) {
    const int bb = i / 288, k = i % 288;
    sf[bb * 300 + k] = h[(size_t)(b0 + bb) * 20736 + g * 288 + k];
  }
  if (threadIdx.x < 128) {
    const int j = threadIdx.x >> 6, o = threadIdx.x & 63;
    sw2[j * 64 + o] = w2[(size_t)(g * 2 + j) * 4608 + g * 64 + o];
  }
  if (threadIdx.x < 2) sb2[threadIdx.x] = b2[g * 2 + threadIdx.x];
  __syncthreads();
  const int bp = threadIdx.x & 15, oq = threadIdx.x >> 4;
  const int o0 = 4 * oq;
  float acc[2][4];
#pragma unroll
  for (int i = 0; i < 2; i++)
#pragma unroll
    for (int j = 0; j < 4; j++) acc[i][j] = 0.f;
  for (int k4 = 0; k4 < 72; k4++) {
    const float4 f0 = *(const float4*)&sf[bp * 300 + 4 * k4];
    const float4 f1 = *(const float4*)&sf[(bp + 16) * 300 + 4 * k4];
#pragma unroll
    for (int j = 0; j < 4; j++) {
      const float4 wr = *(const float4*)&sw1[(o0 + j) * 292 + 4 * k4];
      acc[0][j] = fmaf(f0.x, wr.x, fmaf(f0.y, wr.y, fmaf(f0.z, wr.z, fmaf(f0.w, wr.w, acc[0][j]))));
      acc[1][j] = fmaf(f1.x, wr.x, fmaf(f1.y, wr.y, fmaf(f1.z, wr.z, fmaf(f1.w, wr.w, acc[1][j]))));
    }
  }
#pragma unroll
  for (int j = 0; j < 4; j++) {
    so[bp * 65 + o0 + j] = acc[0][j];
    so[(bp + 16) * 65 + o0 + j] = acc[1][j];
  }
  __syncthreads();
  if (threadIdx.x < 64) {
    const int bb = threadIdx.x >> 1, j = threadIdx.x & 1;
    float a = sb2[j];
#pragma unroll 8
    for (int o = 0; o < 64; o++) a = fmaf(so[bb * 65 + o], sw2[j * 64 + o], a);
    out[(b0 + bb) * 144 + g * 2 + j] = a;
  }
}

extern "C" void kernel_launch(void* const* d_in, const int* in_sizes, int n_in,
                              void* d_out, int out_size, void* d_ws, size_t ws_size,
                              hipStream_t stream) {
  const float* x   = (const float*)d_in[0];
  const float* w1  = (const float*)d_in[1];
  const float* b1  = (const float*)d_in[2];
  const float* w2  = (const float*)d_in[3];
  const float* b2  = (const float*)d_in[4];
  const float* w3  = (const float*)d_in[5];
  const float* b3  = (const float*)d_in[6];
  const float* l1w = (const float*)d_in[7];
  const float* l2w = (const float*)d_in[8];
  const float* l2b = (const float*)d_in[9];
  float* out = (float*)d_out;

  float* h1 = (float*)d_ws;          // 64*576*21*21
  float* h2 = h1 + 16257024;         // 64*1152*9*9
  float* h3 = h2 + 5971968;          // 64*2304*3*3

  conv1_k<<<dim3(64 * NG), 256, 0, stream>>>(x,  w1, b1, h1);
  conv2_k<<<dim3(22 * NG), 256, 0, stream>>>(h1, w2, b2, h2);
  conv3_k<<<dim3(10 * NG), 256, 0, stream>>>(h2, w3, b3, h3);
  lin_k  <<<dim3(2 * NG),  256, 0, stream>>>(h3, l1w, l2w, l2b, out);
}